// Round 1
// baseline (158.496 us; speedup 1.0000x reference)
//
#include <hip/hip_runtime.h>
#include <hip/hip_bf16.h>

// FiLM + 2-layer preact resnet, fully fused. N=65536, H=256, C=512.
// GEMMs in bf16 MFMA (16x16x32), fp32 accum. Weights pre-packed into
// MFMA B-fragment order in d_ws by a tiny prep kernel.

typedef __attribute__((ext_vector_type(8))) short bf16x8;   // 8 bf16 = 4 VGPR
typedef __attribute__((ext_vector_type(4))) float f32x4;    // MFMA C/D

typedef unsigned short ushort_t;
typedef unsigned int uint_t;

__device__ __forceinline__ ushort_t f2bf(float f) {
  union { float f; uint_t u; } v; v.f = f;
  uint_t u = v.u;
  return (ushort_t)((u + 0x7FFFu + ((u >> 16) & 1u)) >> 16);  // RNE
}

// ---------------------------------------------------------------------------
// Pack weights (fp32 row-major [K][Ncols]) into bf16 MFMA-B fragment order:
//   p[((nt*KT + kt)*64 + lane)*8 + j] = W[kt*32 + (lane>>4)*8 + j][nt*16 + (lane&15)]
// so a lane's B-fragment is one contiguous 16B load.
// W_film: K=512,N=512 (nt 0..31, kt 0..15) -> 32768 units
// W1,W2 : K=256,N=256 (nt 0..15, kt 0..7)  ->  8192 units each
// ---------------------------------------------------------------------------
__global__ void pack_weights(const float* __restrict__ Wf,
                             const float* __restrict__ W1,
                             const float* __restrict__ W2,
                             ushort_t* __restrict__ p1,
                             ushort_t* __restrict__ pW1,
                             ushort_t* __restrict__ pW2) {
  int u = blockIdx.x * 256 + threadIdx.x;
  if (u < 32768) {
    int lane = u & 63, rest = u >> 6;
    int kt = rest & 15;         // 16 k-tiles
    int kb = kt * 32 + (lane >> 4) * 8;
    int col = (rest >> 4) * 16 + (lane & 15);
#pragma unroll
    for (int j = 0; j < 8; ++j)
      p1[(size_t)u * 8 + j] = f2bf(Wf[(size_t)(kb + j) * 512 + col]);
  } else if (u < 40960) {
    int v = u - 32768;
    int lane = v & 63;
    int kt = (v >> 6) & 7;      // 8 k-tiles
    int kb = kt * 32 + (lane >> 4) * 8;
    int col = (v >> 9) * 16 + (lane & 15);
#pragma unroll
    for (int j = 0; j < 8; ++j)
      pW1[(size_t)v * 8 + j] = f2bf(W1[(size_t)(kb + j) * 256 + col]);
  } else if (u < 49152) {
    int v = u - 40960;
    int lane = v & 63;
    int kt = (v >> 6) & 7;
    int kb = kt * 32 + (lane >> 4) * 8;
    int col = (v >> 9) * 16 + (lane & 15);
#pragma unroll
    for (int j = 0; j < 8; ++j)
      pW2[(size_t)v * 8 + j] = f2bf(W2[(size_t)(kb + j) * 256 + col]);
  }
}

// ---------------------------------------------------------------------------
// Fused kernel: 1 workgroup = 64 rows. 4 waves; wave w owns output columns
// [w*64, w*64+64). For GEMM1 wave w computes gb columns {w*64..+64} (gamma)
// and {256+w*64..+64} (beta) so FiLM needs no cross-wave exchange.
// LDS (64KB): [0,64K) cond stage (bf16 [64][512], XOR-swizzled);
// after GEMM1: [0,32K) r1, [32K,64K) r2 (bf16 [64][256], XOR-swizzled).
// ---------------------------------------------------------------------------
__global__ __launch_bounds__(256, 2)
void film_fused(const float* __restrict__ x, const float* __restrict__ cond,
                const float* __restrict__ b_film, const float* __restrict__ b1,
                const float* __restrict__ b2,
                const ushort_t* __restrict__ p1, const ushort_t* __restrict__ pW1,
                const ushort_t* __restrict__ pW2, float* __restrict__ out) {
  __shared__ __align__(16) char lds[65536];
  const int r0 = blockIdx.x * 64;
  const int t = threadIdx.x;
  const int w = t >> 6;
  const int l = t & 63;
  const int l15 = l & 15;
  const int lhi = l >> 4;

  // ---- stage cond block -> bf16 LDS, swizzled row-major [64][512]
#pragma unroll
  for (int i = 0; i < 16; ++i) {
    int u = i * 256 + t;
    int row = u >> 6;          // 0..63
    int k8 = u & 63;           // 8-col unit within 512
    const float4* src =
        reinterpret_cast<const float4*>(cond + (size_t)(r0 + row) * 512 + k8 * 8);
    float4 a = src[0];
    float4 b = src[1];
    union { bf16x8 v; ushort_t s[8]; } h;
    h.s[0] = f2bf(a.x); h.s[1] = f2bf(a.y); h.s[2] = f2bf(a.z); h.s[3] = f2bf(a.w);
    h.s[4] = f2bf(b.x); h.s[5] = f2bf(b.y); h.s[6] = f2bf(b.z); h.s[7] = f2bf(b.w);
    int byte = row * 1024 + k8 * 16;
    byte ^= ((row & 15) << 4);
    *reinterpret_cast<bf16x8*>(lds + byte) = h.v;
  }
  __syncthreads();

  // ---- GEMM1: gb = cond @ W_film  (K=512). acc[m][tt]: m=4 row-tiles,
  // tt 0..3 -> gamma n-tiles (w*4+tt), tt 4..7 -> beta n-tiles (16+w*4+tt-4)
  f32x4 acc[4][8];
#pragma unroll
  for (int m = 0; m < 4; ++m)
#pragma unroll
    for (int n = 0; n < 8; ++n) acc[m][n] = (f32x4){0.f, 0.f, 0.f, 0.f};

  for (int kt = 0; kt < 16; ++kt) {
    bf16x8 afr[4];
#pragma unroll
    for (int m = 0; m < 4; ++m) {
      int row = m * 16 + l15;
      int byte = row * 1024 + kt * 64 + lhi * 16;
      byte ^= ((row & 15) << 4);
      afr[m] = *reinterpret_cast<const bf16x8*>(lds + byte);
    }
#pragma unroll
    for (int tt = 0; tt < 8; ++tt) {
      int nt = (tt < 4) ? (w * 4 + tt) : (16 + w * 4 + (tt - 4));
      bf16x8 bfr = *reinterpret_cast<const bf16x8*>(p1 + ((size_t)(nt * 16 + kt) * 64 + l) * 8);
#pragma unroll
      for (int m = 0; m < 4; ++m)
        acc[m][tt] = __builtin_amdgcn_mfma_f32_16x16x32_bf16(afr[m], bfr, acc[m][tt], 0, 0, 0);
    }
  }
  __syncthreads();  // all waves done reading cond LDS

  // ---- FiLM: h = relu(gamma*x + beta) -> bf16 r1 in lds[0,32K)
  float xr[4][4][4];  // saved x for the residual
#pragma unroll
  for (int tt = 0; tt < 4; ++tt) {
    int colg = w * 64 + tt * 16 + l15;
    float bg = b_film[colg];
    float bb = b_film[256 + colg];
#pragma unroll
    for (int m = 0; m < 4; ++m) {
#pragma unroll
      for (int reg = 0; reg < 4; ++reg) {
        int row = m * 16 + lhi * 4 + reg;
        float xv = x[(size_t)(r0 + row) * 256 + colg];
        xr[m][tt][reg] = xv;
        float g = acc[m][tt][reg] + bg;
        float be = acc[m][4 + tt][reg] + bb;
        float h = fmaxf(g * xv + be, 0.f);
        int byte = row * 512 + colg * 2;
        byte ^= ((row & 15) << 4);
        *reinterpret_cast<ushort_t*>(lds + byte) = f2bf(h);
      }
    }
  }
  __syncthreads();

  // ---- GEMM2: h1 = r1 @ W1 + b1, relu -> r2 in lds[32K,64K)
  f32x4 acc2[4][4];
#pragma unroll
  for (int m = 0; m < 4; ++m)
#pragma unroll
    for (int n = 0; n < 4; ++n) acc2[m][n] = (f32x4){0.f, 0.f, 0.f, 0.f};

  for (int kt = 0; kt < 8; ++kt) {
    bf16x8 afr[4];
#pragma unroll
    for (int m = 0; m < 4; ++m) {
      int row = m * 16 + l15;
      int byte = row * 512 + kt * 64 + lhi * 16;
      byte ^= ((row & 15) << 4);
      afr[m] = *reinterpret_cast<const bf16x8*>(lds + byte);
    }
#pragma unroll
    for (int tt = 0; tt < 4; ++tt) {
      int nt = w * 4 + tt;
      bf16x8 bfr = *reinterpret_cast<const bf16x8*>(pW1 + ((size_t)(nt * 8 + kt) * 64 + l) * 8);
#pragma unroll
      for (int m = 0; m < 4; ++m)
        acc2[m][tt] = __builtin_amdgcn_mfma_f32_16x16x32_bf16(afr[m], bfr, acc2[m][tt], 0, 0, 0);
    }
  }
#pragma unroll
  for (int tt = 0; tt < 4; ++tt) {
    int colg = w * 64 + tt * 16 + l15;
    float bias = b1[colg];
#pragma unroll
    for (int m = 0; m < 4; ++m) {
#pragma unroll
      for (int reg = 0; reg < 4; ++reg) {
        int row = m * 16 + lhi * 4 + reg;
        float h = fmaxf(acc2[m][tt][reg] + bias, 0.f);
        int byte = row * 512 + colg * 2;
        byte ^= ((row & 15) << 4);
        *reinterpret_cast<ushort_t*>(lds + 32768 + byte) = f2bf(h);
      }
    }
  }
  __syncthreads();

  // ---- GEMM3: h2 = r2 @ W2 + b2 ; out = h2 + x
#pragma unroll
  for (int m = 0; m < 4; ++m)
#pragma unroll
    for (int n = 0; n < 4; ++n) acc2[m][n] = (f32x4){0.f, 0.f, 0.f, 0.f};

  for (int kt = 0; kt < 8; ++kt) {
    bf16x8 afr[4];
#pragma unroll
    for (int m = 0; m < 4; ++m) {
      int row = m * 16 + l15;
      int byte = row * 512 + kt * 64 + lhi * 16;
      byte ^= ((row & 15) << 4);
      afr[m] = *reinterpret_cast<const bf16x8*>(lds + 32768 + byte);
    }
#pragma unroll
    for (int tt = 0; tt < 4; ++tt) {
      int nt = w * 4 + tt;
      bf16x8 bfr = *reinterpret_cast<const bf16x8*>(pW2 + ((size_t)(nt * 8 + kt) * 64 + l) * 8);
#pragma unroll
      for (int m = 0; m < 4; ++m)
        acc2[m][tt] = __builtin_amdgcn_mfma_f32_16x16x32_bf16(afr[m], bfr, acc2[m][tt], 0, 0, 0);
    }
  }
#pragma unroll
  for (int tt = 0; tt < 4; ++tt) {
    int colg = w * 64 + tt * 16 + l15;
    float bias = b2[colg];
#pragma unroll
    for (int m = 0; m < 4; ++m) {
#pragma unroll
      for (int reg = 0; reg < 4; ++reg) {
        int row = m * 16 + lhi * 4 + reg;
        out[(size_t)(r0 + row) * 256 + colg] = acc2[m][tt][reg] + bias + xr[m][tt][reg];
      }
    }
  }
}

extern "C" void kernel_launch(void* const* d_in, const int* in_sizes, int n_in,
                              void* d_out, int out_size, void* d_ws, size_t ws_size,
                              hipStream_t stream) {
  const float* x      = (const float*)d_in[0];
  const float* cond   = (const float*)d_in[1];
  const float* W_film = (const float*)d_in[2];
  const float* b_film = (const float*)d_in[3];
  const float* W1     = (const float*)d_in[4];
  const float* b1     = (const float*)d_in[5];
  const float* W2     = (const float*)d_in[6];
  const float* b2     = (const float*)d_in[7];
  float* out = (float*)d_out;

  ushort_t* p1  = (ushort_t*)d_ws;      // 512*512 bf16 = 512KB
  ushort_t* pW1 = p1 + 262144;          // 128KB
  ushort_t* pW2 = pW1 + 65536;          // 128KB  (total 768KB of ws)

  hipLaunchKernelGGL(pack_weights, dim3(192), dim3(256), 0, stream,
                     W_film, W1, W2, p1, pW1, pW2);
  hipLaunchKernelGGL(film_fused, dim3(65536 / 64), dim3(256), 0, stream,
                     x, cond, b_film, b1, b2, p1, pW1, pW2, out);
}